// Round 7
// baseline (437.632 us; speedup 1.0000x reference)
//
#include <hip/hip_runtime.h>

// GCNFirst: h[i,:] = (1/deg(i)) * sum over edges (i,p,j) of w[p,j,:]
// weights (r=16, n=100000, e=16) f32; E=3.2M edges; out (n,16) f32.
//
// Bucket multisplit (atomic-free output) + max-MLP gather:
//   P1 hist:  LDS-aggregated histogram of edges per 32-node bucket
//   P2 scan:  single-WG exclusive scan (4096 bins) -> off[], cursor[]
//   P3 split: per-WG LDS hist -> one global atomic per (WG,bucket) reserves a
//             contiguous range -> burst writes of packed edge records
//   P4 accum: one 256-thread WG per 32-node bucket; recs staged in LDS;
//             8x unrolled independent weight gathers (32 lines in flight per
//             wave); LDS f32 accumulate; coalesced normalized store.
//             R6 lesson: gather is miss-LATENCY bound (round-1 proved the
//             path does >=2TB/s); the fix is outstanding misses, not locality.

static constexpr int EDIM   = 16;
static constexpr int NREL   = 16;
static constexpr int BSH    = 5;               // 32 nodes per bucket
static constexpr int BNODES = 1 << BSH;
static constexpr int MAXNB  = 4096;            // supports n <= 131072
static constexpr int EPW    = 32768;           // edges per WG in P1/P3
static constexpr int STG    = 2048;            // recs per chunk in P4

// ---------- P1: bucket histogram ----------
__global__ void hist_kernel(const int* __restrict__ src, int* __restrict__ cnt, int E) {
    __shared__ int h[MAXNB];
    int t = threadIdx.x;
    for (int i = t; i < MAXNB; i += 256) h[i] = 0;
    __syncthreads();
    int base = blockIdx.x * EPW;
    int end = min(base + EPW, E);
    for (int k = base + t; k < end; k += 256) atomicAdd(&h[src[k] >> BSH], 1);
    __syncthreads();
    for (int i = t; i < MAXNB; i += 256) {
        int c = h[i];
        if (c) atomicAdd(&cnt[i], c);
    }
}

// ---------- P2: exclusive scan of nb (<=4096) counters, init cursors ----------
__global__ void scan_kernel(const int* __restrict__ cnt, int* __restrict__ off,
                            int* __restrict__ cursor, int nb) {
    __shared__ int s[1024];
    int t = threadIdx.x;
    int a[4];
    int sum = 0;
#pragma unroll
    for (int q = 0; q < 4; ++q) {
        int idx = 4 * t + q;
        a[q] = (idx < nb) ? cnt[idx] : 0;
        sum += a[q];
    }
    s[t] = sum;
    __syncthreads();
    int acc = sum;
    for (int d = 1; d < 1024; d <<= 1) {
        int x = (t >= d) ? s[t - d] : 0;
        __syncthreads();
        acc += x;
        s[t] = acc;
        __syncthreads();
    }
    int run = acc - sum;  // exclusive base for this thread's 4 bins
#pragma unroll
    for (int q = 0; q < 4; ++q) {
        int idx = 4 * t + q;
        if (idx < nb) { off[idx] = run; cursor[idx] = run; }
        run += a[q];
    }
    if (t == 1023) off[nb] = acc;  // == E (acc of last thread = grand total)
}

// ---------- P3: multisplit scatter of packed records ----------
// rec = (src&31)<<21 | rel<<17 | dst   (dst < 2^17, rel < 16)
__global__ void split_kernel(const int* __restrict__ src, const int* __restrict__ rel,
                             const int* __restrict__ dst, int* __restrict__ cursor,
                             unsigned* __restrict__ recs, int E) {
    __shared__ int h[MAXNB];
    int t = threadIdx.x;
    for (int i = t; i < MAXNB; i += 256) h[i] = 0;
    __syncthreads();
    int base = blockIdx.x * EPW;
    int end = min(base + EPW, E);
    for (int k = base + t; k < end; k += 256) atomicAdd(&h[src[k] >> BSH], 1);
    __syncthreads();
    for (int i = t; i < MAXNB; i += 256) {
        int c = h[i];
        h[i] = c ? atomicAdd(&cursor[i], c) : 0;
    }
    __syncthreads();
    for (int k = base + t; k < end; k += 256) {
        int s = src[k];
        int b = s >> BSH;
        int pos = atomicAdd(&h[b], 1);  // LDS cursor
        recs[pos] = ((unsigned)(s & (BNODES - 1)) << 21) |
                    ((unsigned)rel[k] << 17) | (unsigned)dst[k];
    }
}

// ---------- P4: MLP-8 gather + LDS accumulate + store ----------
__global__ __launch_bounds__(256, 8)
void accum_kernel(const float* __restrict__ w, const int* __restrict__ off,
                  const unsigned* __restrict__ recs, float* __restrict__ out,
                  int n) {
    __shared__ float acc[BNODES * 17];   // stride 17: spread banks
    __shared__ int   degs[BNODES];
    __shared__ unsigned lrec[STG];
    int b = blockIdx.x;
    int t = threadIdx.x;
    for (int i = t; i < BNODES * 17; i += 256) acc[i] = 0.f;
    if (t < BNODES) degs[t] = 0;
    __syncthreads();

    int s0 = off[b], s1 = off[b + 1];
    int g = t >> 4;        // edge subgroup 0..15
    int l = t & 15;        // feature lane

    for (int cbase = s0; cbase < s1; cbase += STG) {
        int cnt = min(STG, s1 - cbase);
        for (int i = t; i < cnt; i += 256) lrec[i] = recs[cbase + i];
        __syncthreads();

        int i = g;
        int lim = cnt - 112;
        for (; i < lim; i += 128) {
            unsigned r0 = lrec[i];
            unsigned r1 = lrec[i + 16];
            unsigned r2 = lrec[i + 32];
            unsigned r3 = lrec[i + 48];
            unsigned r4 = lrec[i + 64];
            unsigned r5 = lrec[i + 80];
            unsigned r6 = lrec[i + 96];
            unsigned r7 = lrec[i + 112];
            int sl0 = (int)((r0 >> 21) & 31u), j0 = (int)((r0 >> 17) & 15u) * n + (int)(r0 & 0x1FFFFu);
            int sl1 = (int)((r1 >> 21) & 31u), j1 = (int)((r1 >> 17) & 15u) * n + (int)(r1 & 0x1FFFFu);
            int sl2 = (int)((r2 >> 21) & 31u), j2 = (int)((r2 >> 17) & 15u) * n + (int)(r2 & 0x1FFFFu);
            int sl3 = (int)((r3 >> 21) & 31u), j3 = (int)((r3 >> 17) & 15u) * n + (int)(r3 & 0x1FFFFu);
            int sl4 = (int)((r4 >> 21) & 31u), j4 = (int)((r4 >> 17) & 15u) * n + (int)(r4 & 0x1FFFFu);
            int sl5 = (int)((r5 >> 21) & 31u), j5 = (int)((r5 >> 17) & 15u) * n + (int)(r5 & 0x1FFFFu);
            int sl6 = (int)((r6 >> 21) & 31u), j6 = (int)((r6 >> 17) & 15u) * n + (int)(r6 & 0x1FFFFu);
            int sl7 = (int)((r7 >> 21) & 31u), j7 = (int)((r7 >> 17) & 15u) * n + (int)(r7 & 0x1FFFFu);
            // 8 independent gathers in flight (32 lines per wave)
            float v0 = w[((size_t)j0 << 4) + l];
            float v1 = w[((size_t)j1 << 4) + l];
            float v2 = w[((size_t)j2 << 4) + l];
            float v3 = w[((size_t)j3 << 4) + l];
            float v4 = w[((size_t)j4 << 4) + l];
            float v5 = w[((size_t)j5 << 4) + l];
            float v6 = w[((size_t)j6 << 4) + l];
            float v7 = w[((size_t)j7 << 4) + l];
            atomicAdd(&acc[sl0 * 17 + l], v0);
            atomicAdd(&acc[sl1 * 17 + l], v1);
            atomicAdd(&acc[sl2 * 17 + l], v2);
            atomicAdd(&acc[sl3 * 17 + l], v3);
            atomicAdd(&acc[sl4 * 17 + l], v4);
            atomicAdd(&acc[sl5 * 17 + l], v5);
            atomicAdd(&acc[sl6 * 17 + l], v6);
            atomicAdd(&acc[sl7 * 17 + l], v7);
            if (l < 8) {
                int slu = (l == 0) ? sl0 : (l == 1) ? sl1 : (l == 2) ? sl2 : (l == 3) ? sl3
                        : (l == 4) ? sl4 : (l == 5) ? sl5 : (l == 6) ? sl6 : sl7;
                atomicAdd(&degs[slu], 1);
            }
        }
        for (; i < cnt; i += 16) {
            unsigned rc = lrec[i];
            int sl = (int)((rc >> 21) & 31u);
            int j = (int)((rc >> 17) & 15u) * n + (int)(rc & 0x1FFFFu);
            float wv = w[((size_t)j << 4) + l];
            atomicAdd(&acc[sl * 17 + l], wv);
            if (l == 0) atomicAdd(&degs[sl], 1);
        }
        __syncthreads();
    }

    // store ALL nodes of this bucket (deg==0 -> 0), so no out memset needed
    for (int i = t; i < BNODES * EDIM; i += 256) {
        int sl = i >> 4;
        int node = (b << BSH) + sl;
        if (node < n) {
            int d = degs[sl];
            float inv = d ? 1.0f / (float)d : 0.0f;
            out[(size_t)node * EDIM + (i & 15)] = acc[sl * 17 + (i & 15)] * inv;
        }
    }
}

// ---------- fallback: round-1 push-atomic path ----------
__global__ void deg_kernel_f(const int* __restrict__ src, float* __restrict__ deg, int E) {
    int k = blockIdx.x * blockDim.x + threadIdx.x;
    if (k < E) atomicAdd(&deg[src[k]], 1.0f);
}
__global__ void scatter_kernel_f(const float* __restrict__ w, const int* __restrict__ src,
                                 const int* __restrict__ rel, const int* __restrict__ dst,
                                 const float* __restrict__ deg, float* __restrict__ out,
                                 int E, int n) {
    long long tid = (long long)blockIdx.x * blockDim.x + threadIdx.x;
    int lane = (int)(tid & 15);
    int k = (int)(tid >> 4);
    if (k >= E) return;
    int s = src[k], p = rel[k], j = dst[k];
    atomicAdd(&out[(size_t)s * EDIM + lane],
              w[((size_t)p * n + j) * EDIM + lane] / deg[s]);
}

extern "C" void kernel_launch(void* const* d_in, const int* in_sizes, int n_in,
                              void* d_out, int out_size, void* d_ws, size_t ws_size,
                              hipStream_t stream) {
    const float* w   = (const float*)d_in[0];
    const int*   src = (const int*)d_in[1];
    const int*   rel = (const int*)d_in[2];
    const int*   dst = (const int*)d_in[3];
    float* out = (float*)d_out;

    int E = in_sizes[1];
    int n = in_sizes[0] / (NREL * EDIM);
    int nb = (n + BNODES - 1) >> BSH;

    // ws layout (ints): cnt[MAXNB] | off[MAXNB+1] | cursor[MAXNB] | recs[E]
    size_t need = ((size_t)(3 * MAXNB + 1) + (size_t)E) * sizeof(int);

    if (nb > MAXNB || n >= (1 << 17) || ws_size < need) {
        float* deg = (float*)d_ws;
        hipMemsetAsync(deg, 0, (size_t)n * sizeof(float), stream);
        hipMemsetAsync(out, 0, (size_t)out_size * sizeof(float), stream);
        deg_kernel_f<<<(E + 255) / 256, 256, 0, stream>>>(src, deg, E);
        long long total = (long long)E * EDIM;
        scatter_kernel_f<<<(int)((total + 255) / 256), 256, 0, stream>>>(w, src, rel, dst, deg, out, E, n);
        return;
    }

    int* cnt    = (int*)d_ws;
    int* off    = cnt + MAXNB;
    int* cursor = off + (MAXNB + 1);
    unsigned* recs = (unsigned*)(cursor + MAXNB);

    hipMemsetAsync(cnt, 0, (size_t)MAXNB * sizeof(int), stream);

    int ewgs = (E + EPW - 1) / EPW;
    hist_kernel <<<ewgs, 256, 0, stream>>>(src, cnt, E);
    scan_kernel <<<1, 1024, 0, stream>>>(cnt, off, cursor, nb);
    split_kernel<<<ewgs, 256, 0, stream>>>(src, rel, dst, cursor, recs, E);
    accum_kernel<<<nb, 256, 0, stream>>>(w, off, recs, out, n);
}

// Round 8
// 137.075 us; speedup vs baseline: 3.1926x; 3.1926x over previous
//
#include <hip/hip_runtime.h>

// GCNFirst: h[i,:] = (1/deg(i)) * sum over edges (i,p,j) of w[p,j,:]
// weights (r=16, n=100000, e=16) f32; E=3.2M edges; out (n,16) f32.
//
// Bucket multisplit + REGISTER-accumulating gather (no LDS atomics in the
// accumulate path — R7 showed the gather rate collapse was LDS same-address
// ds_add serialization, not miss latency):
//   P1 hist:  int4-vectorized histogram of edges per 128-node bucket
//   P2 scan:  single-WG exclusive scan (<=1024 bins) -> off[], cursor[]
//   P3 split: per-WG LDS hist -> one global atomic per (WG,bucket) reserves a
//             contiguous range -> writes packed edge records
//   P4 accum: one 512-thread WG per 128-node bucket. Per chunk: counting-sort
//             recs by LOCAL NODE in LDS (128-bin hist + shfl scan + scatter),
//             then 32 groups x 16 lanes: each group owns 4 nodes, gathers each
//             node's weight rows with unroll-4 MLP into REGISTERS, one
//             coalesced 64B store per node. Degree = sorted range length.

static constexpr int EDIM   = 16;
static constexpr int NREL   = 16;
static constexpr int BSH    = 7;               // 128 nodes per bucket
static constexpr int BNODES = 1 << BSH;
static constexpr int MAXNB  = 1024;            // supports n <= 131072
static constexpr int EPW    = 8192;            // edges per WG in P1/P3
static constexpr int CAP    = 8192;            // recs per chunk in P4 (32KB)

// ---------- P1: bucket histogram (int4 loads) ----------
__global__ void hist_kernel(const int* __restrict__ src, int* __restrict__ cnt, int E) {
    __shared__ int h[MAXNB];
    int t = threadIdx.x;
    for (int i = t; i < MAXNB; i += 256) h[i] = 0;
    __syncthreads();
    int base = blockIdx.x * EPW;
    int end = min(base + EPW, E);
    int nfull = (end - base) >> 2;
    const int4* p4 = (const int4*)(src + base);
    for (int q = t; q < nfull; q += 256) {
        int4 v = p4[q];
        atomicAdd(&h[v.x >> BSH], 1);
        atomicAdd(&h[v.y >> BSH], 1);
        atomicAdd(&h[v.z >> BSH], 1);
        atomicAdd(&h[v.w >> BSH], 1);
    }
    for (int k = base + (nfull << 2) + t; k < end; k += 256) atomicAdd(&h[src[k] >> BSH], 1);
    __syncthreads();
    for (int i = t; i < MAXNB; i += 256) {
        int c = h[i];
        if (c) atomicAdd(&cnt[i], c);
    }
}

// ---------- P2: exclusive scan of nb (<=1024) counters, init cursors ----------
__global__ void scan_kernel(const int* __restrict__ cnt, int* __restrict__ off,
                            int* __restrict__ cursor, int nb) {
    __shared__ int s[1024];
    int t = threadIdx.x;
    int v = (t < nb) ? cnt[t] : 0;
    s[t] = v;
    __syncthreads();
    int acc = v;
    for (int d = 1; d < 1024; d <<= 1) {
        int x = (t >= d) ? s[t - d] : 0;
        __syncthreads();
        acc += x;
        s[t] = acc;
        __syncthreads();
    }
    if (t < nb) { off[t] = acc - v; cursor[t] = acc - v; }
    if (t == 1023) off[nb] = acc;  // == E
}

// ---------- P3: multisplit scatter of packed records (int4 loads) ----------
// rec = (src&127)<<21 | rel<<17 | dst   (dst < 2^17, rel < 16)
__global__ void split_kernel(const int* __restrict__ src, const int* __restrict__ rel,
                             const int* __restrict__ dst, int* __restrict__ cursor,
                             unsigned* __restrict__ recs, int E) {
    __shared__ int h[MAXNB];
    int t = threadIdx.x;
    for (int i = t; i < MAXNB; i += 256) h[i] = 0;
    __syncthreads();
    int base = blockIdx.x * EPW;
    int end = min(base + EPW, E);
    int nfull = (end - base) >> 2;
    const int4* s4 = (const int4*)(src + base);
    for (int q = t; q < nfull; q += 256) {
        int4 v = s4[q];
        atomicAdd(&h[v.x >> BSH], 1);
        atomicAdd(&h[v.y >> BSH], 1);
        atomicAdd(&h[v.z >> BSH], 1);
        atomicAdd(&h[v.w >> BSH], 1);
    }
    for (int k = base + (nfull << 2) + t; k < end; k += 256) atomicAdd(&h[src[k] >> BSH], 1);
    __syncthreads();
    for (int i = t; i < MAXNB; i += 256) {
        int c = h[i];
        h[i] = c ? atomicAdd(&cursor[i], c) : 0;
    }
    __syncthreads();
    const int4* r4 = (const int4*)(rel + base);
    const int4* d4 = (const int4*)(dst + base);
    for (int q = t; q < nfull; q += 256) {
        int4 vs = s4[q], vr = r4[q], vd = d4[q];
        int pos;
        pos = atomicAdd(&h[vs.x >> BSH], 1);
        recs[pos] = ((unsigned)(vs.x & (BNODES - 1)) << 21) | ((unsigned)vr.x << 17) | (unsigned)vd.x;
        pos = atomicAdd(&h[vs.y >> BSH], 1);
        recs[pos] = ((unsigned)(vs.y & (BNODES - 1)) << 21) | ((unsigned)vr.y << 17) | (unsigned)vd.y;
        pos = atomicAdd(&h[vs.z >> BSH], 1);
        recs[pos] = ((unsigned)(vs.z & (BNODES - 1)) << 21) | ((unsigned)vr.z << 17) | (unsigned)vd.z;
        pos = atomicAdd(&h[vs.w >> BSH], 1);
        recs[pos] = ((unsigned)(vs.w & (BNODES - 1)) << 21) | ((unsigned)vr.w << 17) | (unsigned)vd.w;
    }
    for (int k = base + (nfull << 2) + t; k < end; k += 256) {
        int s = src[k];
        int pos = atomicAdd(&h[s >> BSH], 1);
        recs[pos] = ((unsigned)(s & (BNODES - 1)) << 21) | ((unsigned)rel[k] << 17) | (unsigned)dst[k];
    }
}

// ---------- P4: node-sort + register-accumulating gather ----------
__global__ __launch_bounds__(512)
void accum_kernel(const float* __restrict__ w, const int* __restrict__ off,
                  const unsigned* __restrict__ recs, float* __restrict__ out,
                  int n) {
    __shared__ unsigned srt[CAP];
    __shared__ int noff[BNODES + 1];
    __shared__ int ncur[BNODES];
    int b = blockIdx.x;
    int t = threadIdx.x;
    int g = t >> 4;        // group 0..31
    int l = t & 15;        // feature lane

    int s0 = off[b], s1 = off[b + 1];

    float f[4] = {0.f, 0.f, 0.f, 0.f};
    int   d[4] = {0, 0, 0, 0};

    for (int cbase = s0; cbase < s1; cbase += CAP) {
        int cnt = min(CAP, s1 - cbase);

        // node histogram of this chunk
        if (t < BNODES) ncur[t] = 0;
        __syncthreads();
        for (int i = t; i < cnt; i += 512)
            atomicAdd(&ncur[recs[cbase + i] >> 21], 1);
        __syncthreads();
        // exclusive scan of 128 bins by one wave (2 bins/lane, shfl scan)
        if (t < 64) {
            int c0 = ncur[2 * t], c1 = ncur[2 * t + 1];
            int v = c0 + c1;
            for (int dd = 1; dd < 64; dd <<= 1) {
                int x = __shfl_up(v, dd);
                if (t >= dd) v += x;
            }
            int excl = v - (c0 + c1);
            noff[2 * t] = excl;          ncur[2 * t] = excl;
            noff[2 * t + 1] = excl + c0; ncur[2 * t + 1] = excl + c0;
            if (t == 63) noff[BNODES] = v;
        }
        __syncthreads();
        // scatter into node-sorted order
        for (int i = t; i < cnt; i += 512) {
            unsigned rc = recs[cbase + i];
            int pos = atomicAdd(&ncur[rc >> 21], 1);
            srt[pos] = rc;
        }
        __syncthreads();

        // register accumulation: group g owns local nodes g, g+32, g+64, g+96
#pragma unroll
        for (int q = 0; q < 4; ++q) {
            int ln = g + (q << 5);
            int a = noff[ln], e = noff[ln + 1];
            d[q] += e - a;
            float fs = 0.f;
            int i = a;
            for (; i + 3 < e; i += 4) {
                unsigned r0 = srt[i], r1 = srt[i + 1], r2 = srt[i + 2], r3 = srt[i + 3];
                int j0 = (int)((r0 >> 17) & 15u) * n + (int)(r0 & 0x1FFFFu);
                int j1 = (int)((r1 >> 17) & 15u) * n + (int)(r1 & 0x1FFFFu);
                int j2 = (int)((r2 >> 17) & 15u) * n + (int)(r2 & 0x1FFFFu);
                int j3 = (int)((r3 >> 17) & 15u) * n + (int)(r3 & 0x1FFFFu);
                float v0 = w[((size_t)j0 << 4) + l];
                float v1 = w[((size_t)j1 << 4) + l];
                float v2 = w[((size_t)j2 << 4) + l];
                float v3 = w[((size_t)j3 << 4) + l];
                fs += (v0 + v1) + (v2 + v3);
            }
            for (; i < e; ++i) {
                unsigned rc = srt[i];
                int j = (int)((rc >> 17) & 15u) * n + (int)(rc & 0x1FFFFu);
                fs += w[((size_t)j << 4) + l];
            }
            f[q] += fs;
        }
        __syncthreads();  // protect srt/ncur before next chunk
    }

    // store: one 64B row per owned node (deg==0 -> 0); no out memset needed
#pragma unroll
    for (int q = 0; q < 4; ++q) {
        int ln = g + (q << 5);
        int node = (b << BSH) + ln;
        if (node < n) {
            float inv = d[q] ? 1.0f / (float)d[q] : 0.0f;
            out[(size_t)node * EDIM + l] = f[q] * inv;
        }
    }
}

// ---------- fallback: round-1 push-atomic path ----------
__global__ void deg_kernel_f(const int* __restrict__ src, float* __restrict__ deg, int E) {
    int k = blockIdx.x * blockDim.x + threadIdx.x;
    if (k < E) atomicAdd(&deg[src[k]], 1.0f);
}
__global__ void scatter_kernel_f(const float* __restrict__ w, const int* __restrict__ src,
                                 const int* __restrict__ rel, const int* __restrict__ dst,
                                 const float* __restrict__ deg, float* __restrict__ out,
                                 int E, int n) {
    long long tid = (long long)blockIdx.x * blockDim.x + threadIdx.x;
    int lane = (int)(tid & 15);
    int k = (int)(tid >> 4);
    if (k >= E) return;
    int s = src[k], p = rel[k], j = dst[k];
    atomicAdd(&out[(size_t)s * EDIM + lane],
              w[((size_t)p * n + j) * EDIM + lane] / deg[s]);
}

extern "C" void kernel_launch(void* const* d_in, const int* in_sizes, int n_in,
                              void* d_out, int out_size, void* d_ws, size_t ws_size,
                              hipStream_t stream) {
    const float* w   = (const float*)d_in[0];
    const int*   src = (const int*)d_in[1];
    const int*   rel = (const int*)d_in[2];
    const int*   dst = (const int*)d_in[3];
    float* out = (float*)d_out;

    int E = in_sizes[1];
    int n = in_sizes[0] / (NREL * EDIM);
    int nb = (n + BNODES - 1) >> BSH;

    // ws layout (ints): cnt[MAXNB] | off[MAXNB+1] | cursor[MAXNB] | recs[E]
    size_t need = ((size_t)(3 * MAXNB + 1) + (size_t)E) * sizeof(int);

    if (nb > MAXNB || n >= (1 << 17) || ws_size < need) {
        float* deg = (float*)d_ws;
        hipMemsetAsync(deg, 0, (size_t)n * sizeof(float), stream);
        hipMemsetAsync(out, 0, (size_t)out_size * sizeof(float), stream);
        deg_kernel_f<<<(E + 255) / 256, 256, 0, stream>>>(src, deg, E);
        long long total = (long long)E * EDIM;
        scatter_kernel_f<<<(int)((total + 255) / 256), 256, 0, stream>>>(w, src, rel, dst, deg, out, E, n);
        return;
    }

    int* cnt    = (int*)d_ws;
    int* off    = cnt + MAXNB;
    int* cursor = off + (MAXNB + 1);
    unsigned* recs = (unsigned*)(cursor + MAXNB);

    hipMemsetAsync(cnt, 0, (size_t)MAXNB * sizeof(int), stream);

    int ewgs = (E + EPW - 1) / EPW;
    hist_kernel <<<ewgs, 256, 0, stream>>>(src, cnt, E);
    scan_kernel <<<1, 1024, 0, stream>>>(cnt, off, cursor, nb);
    split_kernel<<<ewgs, 256, 0, stream>>>(src, rel, dst, cursor, recs, E);
    accum_kernel<<<nb, 512, 0, stream>>>(w, off, recs, out, n);
}

// Round 9
// 125.484 us; speedup vs baseline: 3.4875x; 1.0924x over previous
//
#include <hip/hip_runtime.h>

// GCNFirst: h[i,:] = (1/deg(i)) * sum over edges (i,p,j) of w[p,j,:]
// weights (r=16, n=100000, e=16) f32; E=3.2M edges; out (n,16) f32.
//
// Bucket multisplit + register-accumulating gather.
//   P1 hist:  int4-vectorized histogram of edges per 128-node bucket (512t)
//   P2 scan:  single-WG exclusive scan (<=1024 bins) -> off[], cursor[]
//   P3 split: per-WG LDS hist -> global atomic reserves contiguous range ->
//             packed records; EPW=16384 so per-bucket bursts avg 64B
//   P4 accum: TWO 256-thread WGs per bucket (one per 64-node half) for
//             occupancy (R8: 782x512 = 3 WG/CU = 56% occ). Per chunk:
//             counting-sort own half's recs by local node (64-bin LDS hist +
//             wave shfl-scan + scatter), then 16 groups x 16 lanes: group owns
//             4 nodes, unroll-8 independent gathers into REGISTERS (no LDS
//             atomics -- R7/R8 proved ds_add serialization was the wall),
//             one coalesced 64B store per node. Degree = sorted range length.

static constexpr int EDIM   = 16;
static constexpr int NREL   = 16;
static constexpr int BSH    = 7;               // 128 nodes per bucket
static constexpr int BNODES = 1 << BSH;
static constexpr int MAXNB  = 1024;            // supports n <= 131072
static constexpr int EPW    = 16384;           // edges per WG in P1/P3
static constexpr int CAP    = 4096;            // recs per chunk in P4 (16KB)

// ---------- P1: bucket histogram (int4 loads, 512 threads) ----------
__global__ void hist_kernel(const int* __restrict__ src, int* __restrict__ cnt, int E) {
    __shared__ int h[MAXNB];
    int t = threadIdx.x;
    for (int i = t; i < MAXNB; i += 512) h[i] = 0;
    __syncthreads();
    int base = blockIdx.x * EPW;
    int end = min(base + EPW, E);
    int nfull = (end - base) >> 2;
    const int4* p4 = (const int4*)(src + base);
    for (int q = t; q < nfull; q += 512) {
        int4 v = p4[q];
        atomicAdd(&h[v.x >> BSH], 1);
        atomicAdd(&h[v.y >> BSH], 1);
        atomicAdd(&h[v.z >> BSH], 1);
        atomicAdd(&h[v.w >> BSH], 1);
    }
    for (int k = base + (nfull << 2) + t; k < end; k += 512) atomicAdd(&h[src[k] >> BSH], 1);
    __syncthreads();
    for (int i = t; i < MAXNB; i += 512) {
        int c = h[i];
        if (c) atomicAdd(&cnt[i], c);
    }
}

// ---------- P2: exclusive scan of nb (<=1024) counters, init cursors ----------
__global__ void scan_kernel(const int* __restrict__ cnt, int* __restrict__ off,
                            int* __restrict__ cursor, int nb) {
    __shared__ int s[1024];
    int t = threadIdx.x;
    int v = (t < nb) ? cnt[t] : 0;
    s[t] = v;
    __syncthreads();
    int acc = v;
    for (int d = 1; d < 1024; d <<= 1) {
        int x = (t >= d) ? s[t - d] : 0;
        __syncthreads();
        acc += x;
        s[t] = acc;
        __syncthreads();
    }
    if (t < nb) { off[t] = acc - v; cursor[t] = acc - v; }
    if (t == 1023) off[nb] = acc;  // == E
}

// ---------- P3: multisplit scatter of packed records (int4, 512 threads) ----------
// rec = (src&127)<<21 | rel<<17 | dst   (dst < 2^17, rel < 16)
__global__ void split_kernel(const int* __restrict__ src, const int* __restrict__ rel,
                             const int* __restrict__ dst, int* __restrict__ cursor,
                             unsigned* __restrict__ recs, int E) {
    __shared__ int h[MAXNB];
    int t = threadIdx.x;
    for (int i = t; i < MAXNB; i += 512) h[i] = 0;
    __syncthreads();
    int base = blockIdx.x * EPW;
    int end = min(base + EPW, E);
    int nfull = (end - base) >> 2;
    const int4* s4 = (const int4*)(src + base);
    for (int q = t; q < nfull; q += 512) {
        int4 v = s4[q];
        atomicAdd(&h[v.x >> BSH], 1);
        atomicAdd(&h[v.y >> BSH], 1);
        atomicAdd(&h[v.z >> BSH], 1);
        atomicAdd(&h[v.w >> BSH], 1);
    }
    for (int k = base + (nfull << 2) + t; k < end; k += 512) atomicAdd(&h[src[k] >> BSH], 1);
    __syncthreads();
    for (int i = t; i < MAXNB; i += 512) {
        int c = h[i];
        h[i] = c ? atomicAdd(&cursor[i], c) : 0;
    }
    __syncthreads();
    const int4* r4 = (const int4*)(rel + base);
    const int4* d4 = (const int4*)(dst + base);
    for (int q = t; q < nfull; q += 512) {
        int4 vs = s4[q], vr = r4[q], vd = d4[q];
        int pos;
        pos = atomicAdd(&h[vs.x >> BSH], 1);
        recs[pos] = ((unsigned)(vs.x & (BNODES - 1)) << 21) | ((unsigned)vr.x << 17) | (unsigned)vd.x;
        pos = atomicAdd(&h[vs.y >> BSH], 1);
        recs[pos] = ((unsigned)(vs.y & (BNODES - 1)) << 21) | ((unsigned)vr.y << 17) | (unsigned)vd.y;
        pos = atomicAdd(&h[vs.z >> BSH], 1);
        recs[pos] = ((unsigned)(vs.z & (BNODES - 1)) << 21) | ((unsigned)vr.z << 17) | (unsigned)vd.z;
        pos = atomicAdd(&h[vs.w >> BSH], 1);
        recs[pos] = ((unsigned)(vs.w & (BNODES - 1)) << 21) | ((unsigned)vr.w << 17) | (unsigned)vd.w;
    }
    for (int k = base + (nfull << 2) + t; k < end; k += 512) {
        int s = src[k];
        int pos = atomicAdd(&h[s >> BSH], 1);
        recs[pos] = ((unsigned)(s & (BNODES - 1)) << 21) | ((unsigned)rel[k] << 17) | (unsigned)dst[k];
    }
}

// ---------- P4: half-bucket node-sort + unroll-8 register gather ----------
__global__ __launch_bounds__(256, 8)
void accum_kernel(const float* __restrict__ w, const int* __restrict__ off,
                  const unsigned* __restrict__ recs, float* __restrict__ out,
                  int n) {
    __shared__ unsigned srt[CAP];
    __shared__ int noff[65];
    __shared__ int ncur[64];
    int b    = blockIdx.x >> 1;
    int half = blockIdx.x & 1;
    int t = threadIdx.x;
    int g = t >> 4;        // group 0..15
    int l = t & 15;        // feature lane

    int s0 = off[b], s1 = off[b + 1];

    float f[4] = {0.f, 0.f, 0.f, 0.f};
    int   d[4] = {0, 0, 0, 0};

    for (int cbase = s0; cbase < s1; cbase += CAP) {
        int cnt = min(CAP, s1 - cbase);

        // histogram of this half's recs (64 bins)
        if (t < 64) ncur[t] = 0;
        __syncthreads();
        for (int i = t; i < cnt; i += 256) {
            int ln = (int)(recs[cbase + i] >> 21);
            if ((ln >> 6) == half) atomicAdd(&ncur[ln & 63], 1);
        }
        __syncthreads();
        // exclusive scan of 64 bins by wave 0
        if (t < 64) {
            int c = ncur[t];
            int v = c;
            for (int dd = 1; dd < 64; dd <<= 1) {
                int x = __shfl_up(v, dd);
                if (t >= dd) v += x;
            }
            noff[t] = v - c;
            ncur[t] = v - c;
            if (t == 63) noff[64] = v;
        }
        __syncthreads();
        // scatter own half's recs into node-sorted order
        for (int i = t; i < cnt; i += 256) {
            unsigned rc = recs[cbase + i];
            int ln = (int)(rc >> 21);
            if ((ln >> 6) == half) {
                int pos = atomicAdd(&ncur[ln & 63], 1);
                srt[pos] = rc;
            }
        }
        __syncthreads();

        // register accumulation: group g owns half-local nodes g, g+16, g+32, g+48
#pragma unroll
        for (int q = 0; q < 4; ++q) {
            int ln = g + (q << 4);
            int a = noff[ln], e = noff[ln + 1];
            d[q] += e - a;
            float fs = 0.f;
            int i = a;
            for (; i + 7 < e; i += 8) {
                unsigned r0 = srt[i],     r1 = srt[i + 1], r2 = srt[i + 2], r3 = srt[i + 3];
                unsigned r4 = srt[i + 4], r5 = srt[i + 5], r6 = srt[i + 6], r7 = srt[i + 7];
                int j0 = (int)((r0 >> 17) & 15u) * n + (int)(r0 & 0x1FFFFu);
                int j1 = (int)((r1 >> 17) & 15u) * n + (int)(r1 & 0x1FFFFu);
                int j2 = (int)((r2 >> 17) & 15u) * n + (int)(r2 & 0x1FFFFu);
                int j3 = (int)((r3 >> 17) & 15u) * n + (int)(r3 & 0x1FFFFu);
                int j4 = (int)((r4 >> 17) & 15u) * n + (int)(r4 & 0x1FFFFu);
                int j5 = (int)((r5 >> 17) & 15u) * n + (int)(r5 & 0x1FFFFu);
                int j6 = (int)((r6 >> 17) & 15u) * n + (int)(r6 & 0x1FFFFu);
                int j7 = (int)((r7 >> 17) & 15u) * n + (int)(r7 & 0x1FFFFu);
                float v0 = w[((size_t)j0 << 4) + l];
                float v1 = w[((size_t)j1 << 4) + l];
                float v2 = w[((size_t)j2 << 4) + l];
                float v3 = w[((size_t)j3 << 4) + l];
                float v4 = w[((size_t)j4 << 4) + l];
                float v5 = w[((size_t)j5 << 4) + l];
                float v6 = w[((size_t)j6 << 4) + l];
                float v7 = w[((size_t)j7 << 4) + l];
                fs += ((v0 + v1) + (v2 + v3)) + ((v4 + v5) + (v6 + v7));
            }
            for (; i < e; ++i) {
                unsigned rc = srt[i];
                int j = (int)((rc >> 17) & 15u) * n + (int)(rc & 0x1FFFFu);
                fs += w[((size_t)j << 4) + l];
            }
            f[q] += fs;
        }
        __syncthreads();  // protect srt/ncur before next chunk
    }

    // store: one 64B row per owned node (deg==0 -> 0); no out memset needed
#pragma unroll
    for (int q = 0; q < 4; ++q) {
        int node = (b << BSH) + (half << 6) + g + (q << 4);
        if (node < n) {
            float inv = d[q] ? 1.0f / (float)d[q] : 0.0f;
            out[(size_t)node * EDIM + l] = f[q] * inv;
        }
    }
}

// ---------- fallback: round-1 push-atomic path ----------
__global__ void deg_kernel_f(const int* __restrict__ src, float* __restrict__ deg, int E) {
    int k = blockIdx.x * blockDim.x + threadIdx.x;
    if (k < E) atomicAdd(&deg[src[k]], 1.0f);
}
__global__ void scatter_kernel_f(const float* __restrict__ w, const int* __restrict__ src,
                                 const int* __restrict__ rel, const int* __restrict__ dst,
                                 const float* __restrict__ deg, float* __restrict__ out,
                                 int E, int n) {
    long long tid = (long long)blockIdx.x * blockDim.x + threadIdx.x;
    int lane = (int)(tid & 15);
    int k = (int)(tid >> 4);
    if (k >= E) return;
    int s = src[k], p = rel[k], j = dst[k];
    atomicAdd(&out[(size_t)s * EDIM + lane],
              w[((size_t)p * n + j) * EDIM + lane] / deg[s]);
}

extern "C" void kernel_launch(void* const* d_in, const int* in_sizes, int n_in,
                              void* d_out, int out_size, void* d_ws, size_t ws_size,
                              hipStream_t stream) {
    const float* w   = (const float*)d_in[0];
    const int*   src = (const int*)d_in[1];
    const int*   rel = (const int*)d_in[2];
    const int*   dst = (const int*)d_in[3];
    float* out = (float*)d_out;

    int E = in_sizes[1];
    int n = in_sizes[0] / (NREL * EDIM);
    int nb = (n + BNODES - 1) >> BSH;

    // ws layout (ints): cnt[MAXNB] | off[MAXNB+1] | cursor[MAXNB] | recs[E]
    size_t need = ((size_t)(3 * MAXNB + 1) + (size_t)E) * sizeof(int);

    if (nb > MAXNB || n >= (1 << 17) || ws_size < need) {
        float* deg = (float*)d_ws;
        hipMemsetAsync(deg, 0, (size_t)n * sizeof(float), stream);
        hipMemsetAsync(out, 0, (size_t)out_size * sizeof(float), stream);
        deg_kernel_f<<<(E + 255) / 256, 256, 0, stream>>>(src, deg, E);
        long long total = (long long)E * EDIM;
        scatter_kernel_f<<<(int)((total + 255) / 256), 256, 0, stream>>>(w, src, rel, dst, deg, out, E, n);
        return;
    }

    int* cnt    = (int*)d_ws;
    int* off    = cnt + MAXNB;
    int* cursor = off + (MAXNB + 1);
    unsigned* recs = (unsigned*)(cursor + MAXNB);

    hipMemsetAsync(cnt, 0, (size_t)MAXNB * sizeof(int), stream);

    int ewgs = (E + EPW - 1) / EPW;
    hist_kernel <<<ewgs, 512, 0, stream>>>(src, cnt, E);
    scan_kernel <<<1, 1024, 0, stream>>>(cnt, off, cursor, nb);
    split_kernel<<<ewgs, 512, 0, stream>>>(src, rel, dst, cursor, recs, E);
    accum_kernel<<<nb * 2, 256, 0, stream>>>(w, off, recs, out, n);
}